// Round 1
// baseline (304.199 us; speedup 1.0000x reference)
//
#include <hip/hip_runtime.h>
#include <math.h>

#define TT 512      // timesteps
#define HB 16       // hidden size
#define GB 4        // batches per 64-thread block

__device__ __forceinline__ float fast_rcp(float v) { return __builtin_amdgcn_rcpf(v); }
__device__ __forceinline__ float sigm(float v) { return fast_rcp(1.0f + __expf(-v)); }
__device__ __forceinline__ float tanh_fast(float v) {
    float a = fabsf(v);
    float e = __expf(2.0f * a);               // e in [1, inf]; inf is safe below
    float t = 1.0f - 2.0f * fast_rcp(e + 1.0f);
    return copysignf(t, v);
}

__global__ __launch_bounds__(64, 1)
void lstm2_fused(const float* __restrict__ x,
                 const float* __restrict__ W_ih0, const float* __restrict__ W_hh0,
                 const float* __restrict__ b_ih0, const float* __restrict__ b_hh0,
                 const float* __restrict__ W_ih1, const float* __restrict__ W_hh1,
                 const float* __restrict__ b_ih1, const float* __restrict__ b_hh1,
                 const float* __restrict__ W_fc,  const float* __restrict__ b_fc,
                 float* __restrict__ out)
{
    const int tid = threadIdx.x;
    const int grp = tid >> 4;          // batch within block (0..3)
    const int j   = tid & 15;          // hidden unit owned by this lane
    const int b   = blockIdx.x * GB + grp;

    // ---- loop-invariant weights in registers (192 + small) ----
    float wh0[4][16], wi1[4][16], wh1[4][16];
    float wx0[4], bb0[4], bb1[4];
    #pragma unroll
    for (int g = 0; g < 4; ++g) {
        const int row = g * HB + j;    // PyTorch gate order i,f,g,o
        wx0[g] = W_ih0[row];           // D_IN == 1
        bb0[g] = b_ih0[row] + b_hh0[row];
        bb1[g] = b_ih1[row] + b_hh1[row];
        #pragma unroll
        for (int k = 0; k < 16; k += 4) {
            float4 a = *(const float4*)&W_hh0[row * 16 + k];
            wh0[g][k] = a.x; wh0[g][k+1] = a.y; wh0[g][k+2] = a.z; wh0[g][k+3] = a.w;
            float4 bq = *(const float4*)&W_ih1[row * 16 + k];
            wi1[g][k] = bq.x; wi1[g][k+1] = bq.y; wi1[g][k+2] = bq.z; wi1[g][k+3] = bq.w;
            float4 cq = *(const float4*)&W_hh1[row * 16 + k];
            wh1[g][k] = cq.x; wh1[g][k+1] = cq.y; wh1[g][k+2] = cq.z; wh1[g][k+3] = cq.w;
        }
    }
    const float wfc = W_fc[j];
    const float bfc = b_fc[0];

    // ---- per-group h broadcast buffers ----
    __shared__ float h0s[GB][16];
    __shared__ float h1s[GB][16];
    h0s[grp][j] = 0.0f;
    h1s[grp][j] = 0.0f;
    float h0 = 0.0f, c0 = 0.0f, h1 = 0.0f, c1 = 0.0f;
    __syncthreads();

    const float* xb = x + (size_t)b * TT;
    float4 xq = *(const float4*)xb;

    // iteration s: layer0 step s (h0^{s+1}) + layer1 step s-1 (h1^{s}); layers skewed for ILP
    auto STEP = [&](float xi, bool doL1) {
        float hv0[16], hv1[16];
        #pragma unroll
        for (int k = 0; k < 16; k += 4) {
            float4 a = *(const float4*)&h0s[grp][k];
            hv0[k] = a.x; hv0[k+1] = a.y; hv0[k+2] = a.z; hv0[k+3] = a.w;
            float4 bq = *(const float4*)&h1s[grp][k];
            hv1[k] = bq.x; hv1[k+1] = bq.y; hv1[k+2] = bq.z; hv1[k+3] = bq.w;
        }
        float acc0[4], acc1[4];
        #pragma unroll
        for (int g = 0; g < 4; ++g) {
            acc0[g] = fmaf(xi, wx0[g], bb0[g]);
            acc1[g] = bb1[g];
        }
        #pragma unroll
        for (int k = 0; k < 16; ++k) {
            #pragma unroll
            for (int g = 0; g < 4; ++g) {
                acc0[g] = fmaf(wh0[g][k], hv0[k], acc0[g]);
                acc1[g] = fmaf(wi1[g][k], hv0[k], acc1[g]);
                acc1[g] = fmaf(wh1[g][k], hv1[k], acc1[g]);
            }
        }
        float i0 = sigm(acc0[0]), f0 = sigm(acc0[1]);
        float g0 = tanh_fast(acc0[2]), o0 = sigm(acc0[3]);
        c0 = fmaf(f0, c0, i0 * g0);
        h0 = o0 * tanh_fast(c0);
        if (doL1) {
            float i1 = sigm(acc1[0]), f1 = sigm(acc1[1]);
            float g1 = tanh_fast(acc1[2]), o1 = sigm(acc1[3]);
            c1 = fmaf(f1, c1, i1 * g1);
            h1 = o1 * tanh_fast(c1);
        }
        __syncthreads();
        h0s[grp][j] = h0;
        h1s[grp][j] = h1;
        __syncthreads();
    };

    for (int i = 0; i < TT; i += 4) {
        float4 xn = xq;
        if (i + 4 < TT) xn = *(const float4*)(xb + i + 4);
        STEP(xq.x, i > 0);
        STEP(xq.y, true);
        STEP(xq.z, true);
        STEP(xq.w, true);
        xq = xn;
    }

    // ---- final layer-1 step: h1^{512} from (h1^{511}, h0^{512}) ----
    {
        float hv0[16], hv1[16];
        #pragma unroll
        for (int k = 0; k < 16; k += 4) {
            float4 a = *(const float4*)&h0s[grp][k];
            hv0[k] = a.x; hv0[k+1] = a.y; hv0[k+2] = a.z; hv0[k+3] = a.w;
            float4 bq = *(const float4*)&h1s[grp][k];
            hv1[k] = bq.x; hv1[k+1] = bq.y; hv1[k+2] = bq.z; hv1[k+3] = bq.w;
        }
        float acc1[4];
        #pragma unroll
        for (int g = 0; g < 4; ++g) acc1[g] = bb1[g];
        #pragma unroll
        for (int k = 0; k < 16; ++k) {
            #pragma unroll
            for (int g = 0; g < 4; ++g) {
                acc1[g] = fmaf(wi1[g][k], hv0[k], acc1[g]);
                acc1[g] = fmaf(wh1[g][k], hv1[k], acc1[g]);
            }
        }
        float i1 = sigm(acc1[0]), f1 = sigm(acc1[1]);
        float g1 = tanh_fast(acc1[2]), o1 = sigm(acc1[3]);
        c1 = fmaf(f1, c1, i1 * g1);
        h1 = o1 * tanh_fast(c1);
    }

    // ---- FC: out[b] = sum_j h1_j * W_fc[j] + b_fc, reduce within 16-lane group ----
    float p = h1 * wfc;
    #pragma unroll
    for (int m = 1; m < 16; m <<= 1) p += __shfl_xor(p, m, 16);
    if (j == 0) out[b] = p + bfc;
}

extern "C" void kernel_launch(void* const* d_in, const int* in_sizes, int n_in,
                              void* d_out, int out_size, void* d_ws, size_t ws_size,
                              hipStream_t stream) {
    const float* x     = (const float*)d_in[0];
    const float* W_ih0 = (const float*)d_in[1];
    const float* W_hh0 = (const float*)d_in[2];
    const float* b_ih0 = (const float*)d_in[3];
    const float* b_hh0 = (const float*)d_in[4];
    const float* W_ih1 = (const float*)d_in[5];
    const float* W_hh1 = (const float*)d_in[6];
    const float* b_ih1 = (const float*)d_in[7];
    const float* b_hh1 = (const float*)d_in[8];
    const float* W_fc  = (const float*)d_in[9];
    const float* b_fc  = (const float*)d_in[10];
    float* out = (float*)d_out;

    dim3 grid(4096 / GB), block(64);
    hipLaunchKernelGGL(lstm2_fused, grid, block, 0, stream,
                       x, W_ih0, W_hh0, b_ih0, b_hh0,
                       W_ih1, W_hh1, b_ih1, b_hh1, W_fc, b_fc, out);
}

// Round 2
// 289.578 us; speedup vs baseline: 1.0505x; 1.0505x over previous
//
#include <hip/hip_runtime.h>
#include <math.h>

#define TT 512
typedef float f32x2 __attribute__((ext_vector_type(2)));

#define LOG2E 1.4426950408889634f

__device__ __forceinline__ float fast_rcp(float v)  { return __builtin_amdgcn_rcpf(v); }
__device__ __forceinline__ float fast_exp2(float v) { return __builtin_amdgcn_exp2f(v); }

// One wave per batch element. Lane l owns gate-row l (g = l>>4: 0=i,1=f,2=g,3=o; j = l&15)
// of W_hh0, W_ih1, W_hh1 (48 weight floats -> VGPRs, no AGPR shuttle).
// h0/h1 broadcast through 32 floats of LDS (same-address reads = bank broadcast).
__global__ __launch_bounds__(64, 4)
void lstm2_wave(const float* __restrict__ x,
                const float* __restrict__ W_ih0, const float* __restrict__ W_hh0,
                const float* __restrict__ b_ih0, const float* __restrict__ b_hh0,
                const float* __restrict__ W_ih1, const float* __restrict__ W_hh1,
                const float* __restrict__ b_ih1, const float* __restrict__ b_hh1,
                const float* __restrict__ W_fc,  const float* __restrict__ b_fc,
                float* __restrict__ out)
{
    const int l = threadIdx.x;
    const int g = l >> 4;
    const int j = l & 15;
    const int b = blockIdx.x;

    // per-lane weights: row l of each matrix, packed as f32x2
    f32x2 wh0[8], wi1[8], wh1[8];
    #pragma unroll
    for (int k = 0; k < 8; ++k) {
        wh0[k] = *(const f32x2*)&W_hh0[l * 16 + 2 * k];
        wi1[k] = *(const f32x2*)&W_ih1[l * 16 + 2 * k];
        wh1[k] = *(const f32x2*)&W_hh1[l * 16 + 2 * k];
    }
    const float wx0 = W_ih0[l];                    // D_IN == 1
    const float bb0 = b_ih0[l] + b_hh0[l];
    const float bb1 = b_ih1[l] + b_hh1[l];

    // unified activation constants: sigmoid lanes (g!=2): t=1/(1+e^-x); tanh lanes: 2t'-1 with 2x
    const bool  isT = (g == 2);
    const float Ca  = isT ? (-2.0f * LOG2E) : (-LOG2E);
    const float Aa  = isT ? 2.0f : 1.0f;
    const float Ba  = isT ? -1.0f : 0.0f;

    // hs[0:16)=h0, [16:32)=h1, [32:64)=trash (even-gate lanes dump here -> branchless write)
    __shared__ float hs[64];
    hs[l] = 0.0f;
    const int waddr = (g == 1) ? j : (g == 3) ? (16 + j) : (32 + l % 32);
    float cs0 = 0.0f, cs1 = 0.0f;
    __syncthreads();

    const float* xb = x + (size_t)b * TT;
    float4 xq = *(const float4*)xb;

    auto STEP = [&](float xi, bool doL1) {
        // broadcast read of h0, h1 (all lanes same address)
        f32x2 h0v[8], h1v[8];
        #pragma unroll
        for (int k = 0; k < 4; ++k) {
            float4 q0 = *(const float4*)&hs[4 * k];
            h0v[2*k]   = f32x2{q0.x, q0.y};
            h0v[2*k+1] = f32x2{q0.z, q0.w};
            float4 q1 = *(const float4*)&hs[16 + 4 * k];
            h1v[2*k]   = f32x2{q1.x, q1.y};
            h1v[2*k+1] = f32x2{q1.z, q1.w};
        }
        f32x2 a0 = {fmaf(xi, wx0, bb0), 0.0f};
        f32x2 a1 = {bb1, 0.0f};
        #pragma unroll
        for (int k = 0; k < 8; ++k) {
            a0 = __builtin_elementwise_fma(wh0[k], h0v[k], a0);
            a1 = __builtin_elementwise_fma(wi1[k], h0v[k], a1);
            a1 = __builtin_elementwise_fma(wh1[k], h1v[k], a1);
        }
        const float acc0 = a0.x + a0.y;
        const float acc1 = a1.x + a1.y;

        // per-lane activation of own gate (no divergence; constants differ per lane)
        const float act0 = fmaf(Aa, fast_rcp(1.0f + fast_exp2(acc0 * Ca)), Ba);
        const float act1 = fmaf(Aa, fast_rcp(1.0f + fast_exp2(acc1 * Ca)), Ba);

        // cross-lane: xor32 pairs (i<->g, f<->o); xor16 moves i*g product to the f/o lanes
        const float sw0 = __shfl_xor(act0, 32);
        const float sw1 = __shfl_xor(act1, 32);
        const float pr0 = act0 * sw0;              // on g=0/2 lanes: i*g
        const float pr1 = act1 * sw1;
        const float xp0 = __shfl_xor(pr0, 16);     // lane(1,j) <- (0,j): i*g
        const float xp1 = __shfl_xor(pr1, 16);     // lane(3,j) <- (2,j): i1*g1
        const float c0n = fmaf(act0, cs0, xp0);    // valid on g==1 (act0 = f)
        const float c1n = fmaf(sw1, cs1, xp1);     // valid on g==3 (sw1  = f1)
        cs0 = c0n;
        if (doL1) cs1 = c1n;

        // shared tanh pass: lanes g==1 do tanh(c0), others tanh(c1)
        const float tin = (g == 1) ? cs0 : cs1;
        const float aa = fabsf(tin);
        const float e  = fast_exp2(aa * (2.0f * LOG2E));
        float th = fmaf(-2.0f, fast_rcp(e + 1.0f), 1.0f);
        th = copysignf(th, tin);
        const float h0n = sw0 * th;                // g==1: o0 * tanh(c0)
        const float h1n = act1 * th;               // g==3: o1 * tanh(c1); ==0 before first L1 step

        hs[waddr] = (g == 1) ? h0n : h1n;          // single-wave: DS in-order, no barrier needed
    };

    for (int t0 = 0; t0 < TT; t0 += 4) {
        float4 xn = xq;
        if (t0 + 4 < TT) xn = *(const float4*)(xb + t0 + 4);
        STEP(xq.x, t0 != 0);
        STEP(xq.y, true);
        STEP(xq.z, true);
        STEP(xq.w, true);
        xq = xn;
    }

    // final L1 step: z_511 = cell(z_510, y_511)
    {
        f32x2 h0v[8], h1v[8];
        #pragma unroll
        for (int k = 0; k < 4; ++k) {
            float4 q0 = *(const float4*)&hs[4 * k];
            h0v[2*k]   = f32x2{q0.x, q0.y};
            h0v[2*k+1] = f32x2{q0.z, q0.w};
            float4 q1 = *(const float4*)&hs[16 + 4 * k];
            h1v[2*k]   = f32x2{q1.x, q1.y};
            h1v[2*k+1] = f32x2{q1.z, q1.w};
        }
        f32x2 a1 = {bb1, 0.0f};
        #pragma unroll
        for (int k = 0; k < 8; ++k) {
            a1 = __builtin_elementwise_fma(wi1[k], h0v[k], a1);
            a1 = __builtin_elementwise_fma(wh1[k], h1v[k], a1);
        }
        const float acc1 = a1.x + a1.y;
        const float act1 = fmaf(Aa, fast_rcp(1.0f + fast_exp2(acc1 * Ca)), Ba);
        const float sw1 = __shfl_xor(act1, 32);
        const float pr1 = act1 * sw1;
        const float xp1 = __shfl_xor(pr1, 16);
        cs1 = fmaf(sw1, cs1, xp1);                 // valid on g==3
        const float aa = fabsf(cs1);
        const float e  = fast_exp2(aa * (2.0f * LOG2E));
        float th = fmaf(-2.0f, fast_rcp(e + 1.0f), 1.0f);
        th = copysignf(th, cs1);
        const float h1fin = act1 * th;             // valid on g==3

        // FC: out[b] = sum_j h1_j * W_fc[j] + b_fc
        float p = (g == 3) ? h1fin * W_fc[j] : 0.0f;
        #pragma unroll
        for (int m = 1; m < 64; m <<= 1) p += __shfl_xor(p, m);
        if (l == 0) out[b] = p + b_fc[0];
    }
}

extern "C" void kernel_launch(void* const* d_in, const int* in_sizes, int n_in,
                              void* d_out, int out_size, void* d_ws, size_t ws_size,
                              hipStream_t stream) {
    const float* x     = (const float*)d_in[0];
    const float* W_ih0 = (const float*)d_in[1];
    const float* W_hh0 = (const float*)d_in[2];
    const float* b_ih0 = (const float*)d_in[3];
    const float* b_hh0 = (const float*)d_in[4];
    const float* W_ih1 = (const float*)d_in[5];
    const float* W_hh1 = (const float*)d_in[6];
    const float* b_ih1 = (const float*)d_in[7];
    const float* b_hh1 = (const float*)d_in[8];
    const float* W_fc  = (const float*)d_in[9];
    const float* b_fc  = (const float*)d_in[10];
    float* out = (float*)d_out;

    dim3 grid(4096), block(64);
    hipLaunchKernelGGL(lstm2_wave, grid, block, 0, stream,
                       x, W_ih0, W_hh0, b_ih0, b_hh0,
                       W_ih1, W_hh1, b_ih1, b_hh1, W_fc, b_fc, out);
}

// Round 4
// 268.605 us; speedup vs baseline: 1.1325x; 1.0781x over previous
//
#include <hip/hip_runtime.h>
#include <math.h>

#define TT 512
typedef float f32x2 __attribute__((ext_vector_type(2)));

#define LOG2E 1.4426950408889634f

__device__ __forceinline__ float fast_rcp(float v)  { return __builtin_amdgcn_rcpf(v); }
__device__ __forceinline__ float fast_exp2(float v) { return __builtin_amdgcn_exp2f(v); }

// quad_perm DPP: xor1 = [1,0,3,2] = 0xB1 ; xor2 = [2,3,0,1] = 0x4E
template<int CTRL>
__device__ __forceinline__ float dppq(float v) {
    return __int_as_float(__builtin_amdgcn_update_dpp(
        __float_as_int(v), __float_as_int(v), CTRL, 0xF, 0xF, false));
}

#define FMA2(A, B, C) __builtin_elementwise_fma((A), (B), (C))

// One wave per batch element. Lane l = 4*j + g (g: 0=i,1=f,2=g,3=o ; j = hidden unit).
// Lane owns weight row g*16+j of W_hh0 / W_ih1 / W_hh1 (24 named f32x2 regs, asm-pinned).
// h0,h1 broadcast through 32 floats of LDS; cross-gate combines via quad_perm DPP (VALU pipe).
// Arithmetic order is bit-identical to the round-1 kernel that passed.
__global__ __launch_bounds__(64, 4)
void lstm2_wave(const float* __restrict__ x,
                const float* __restrict__ W_ih0, const float* __restrict__ W_hh0,
                const float* __restrict__ b_ih0, const float* __restrict__ b_hh0,
                const float* __restrict__ W_ih1, const float* __restrict__ W_hh1,
                const float* __restrict__ b_ih1, const float* __restrict__ b_hh1,
                const float* __restrict__ W_fc,  const float* __restrict__ b_fc,
                float* __restrict__ out)
{
    const int l = threadIdx.x;
    const int g = l & 3;           // gate: 0=i,1=f,2=g,3=o
    const int j = l >> 2;          // hidden unit
    const int b = blockIdx.x;
    const int row = g * 16 + j;    // PyTorch gate-order row

    // ---- per-lane weights: row of each matrix as named f32x2 ----
    f32x2 wa0 = *(const f32x2*)&W_hh0[row * 16 +  0];
    f32x2 wa1 = *(const f32x2*)&W_hh0[row * 16 +  2];
    f32x2 wa2 = *(const f32x2*)&W_hh0[row * 16 +  4];
    f32x2 wa3 = *(const f32x2*)&W_hh0[row * 16 +  6];
    f32x2 wa4 = *(const f32x2*)&W_hh0[row * 16 +  8];
    f32x2 wa5 = *(const f32x2*)&W_hh0[row * 16 + 10];
    f32x2 wa6 = *(const f32x2*)&W_hh0[row * 16 + 12];
    f32x2 wa7 = *(const f32x2*)&W_hh0[row * 16 + 14];
    f32x2 wb0 = *(const f32x2*)&W_ih1[row * 16 +  0];
    f32x2 wb1 = *(const f32x2*)&W_ih1[row * 16 +  2];
    f32x2 wb2 = *(const f32x2*)&W_ih1[row * 16 +  4];
    f32x2 wb3 = *(const f32x2*)&W_ih1[row * 16 +  6];
    f32x2 wb4 = *(const f32x2*)&W_ih1[row * 16 +  8];
    f32x2 wb5 = *(const f32x2*)&W_ih1[row * 16 + 10];
    f32x2 wb6 = *(const f32x2*)&W_ih1[row * 16 + 12];
    f32x2 wb7 = *(const f32x2*)&W_ih1[row * 16 + 14];
    f32x2 wc0 = *(const f32x2*)&W_hh1[row * 16 +  0];
    f32x2 wc1 = *(const f32x2*)&W_hh1[row * 16 +  2];
    f32x2 wc2 = *(const f32x2*)&W_hh1[row * 16 +  4];
    f32x2 wc3 = *(const f32x2*)&W_hh1[row * 16 +  6];
    f32x2 wc4 = *(const f32x2*)&W_hh1[row * 16 +  8];
    f32x2 wc5 = *(const f32x2*)&W_hh1[row * 16 + 10];
    f32x2 wc6 = *(const f32x2*)&W_hh1[row * 16 + 12];
    f32x2 wc7 = *(const f32x2*)&W_hh1[row * 16 + 14];
    const float wx0 = W_ih0[row];                    // D_IN == 1
    const float bb0 = b_ih0[row] + b_hh0[row];
    const float bb1 = b_ih1[row] + b_hh1[row];

    // pin weight VALUES into VGPRs: compiler cannot rematerialize the global
    // loads inside the loop (the round-1 FETCH-doubling failure mode)
    asm volatile("" :
        "+v"(wa0), "+v"(wa1), "+v"(wa2), "+v"(wa3),
        "+v"(wa4), "+v"(wa5), "+v"(wa6), "+v"(wa7),
        "+v"(wb0), "+v"(wb1), "+v"(wb2), "+v"(wb3),
        "+v"(wb4), "+v"(wb5), "+v"(wb6), "+v"(wb7),
        "+v"(wc0), "+v"(wc1), "+v"(wc2), "+v"(wc3),
        "+v"(wc4), "+v"(wc5), "+v"(wc6), "+v"(wc7));

    // unified activation constants (per-lane; branchless):
    // sigmoid lanes: 1/(1+2^(-x*log2e)); tanh lane (g==2): 2/(1+2^(-2x*log2e)) - 1
    const bool  isT = (g == 2);
    const bool  isF = (g == 1);
    const float Ca  = isT ? (-2.0f * LOG2E) : (-LOG2E);
    const float Aa  = isT ? 2.0f : 1.0f;
    const float Ba  = isT ? -1.0f : 0.0f;
    const float C2P = 2.0f * LOG2E;

    // hs[0:16)=h0, hs[16:32)=h1, [32:48)=trash for even lanes (2-way alias = free)
    __shared__ float hs[48];
    if (l < 48) hs[l] = 0.0f;
    const int wslot = (l & 1) ? (((l & 2) << 3) | j) : (32 + j);
    float cs0 = 0.0f, cs1 = 0.0f;
    __syncthreads();

    const float* xb = x + (size_t)b * TT;
    float4 xq = *(const float4*)xb;

#define LSTM_STEP(XI, DO_L1)                                                   \
  {                                                                            \
    const float4 q0 = *(const float4*)&hs[ 0];                                 \
    const float4 q1 = *(const float4*)&hs[ 4];                                 \
    const float4 q2 = *(const float4*)&hs[ 8];                                 \
    const float4 q3 = *(const float4*)&hs[12];                                 \
    const float4 r0 = *(const float4*)&hs[16];                                 \
    const float4 r1 = *(const float4*)&hs[20];                                 \
    const float4 r2 = *(const float4*)&hs[24];                                 \
    const float4 r3 = *(const float4*)&hs[28];                                 \
    f32x2 a0 = {fmaf((XI), wx0, bb0), 0.0f};                                   \
    f32x2 a1 = {bb1, 0.0f};                                                    \
    f32x2 h;                                                                   \
    h = f32x2{q0.x, q0.y};                                                     \
    a0 = FMA2(wa0, h, a0); a1 = FMA2(wb0, h, a1);                              \
    h = f32x2{r0.x, r0.y}; a1 = FMA2(wc0, h, a1);                              \
    h = f32x2{q0.z, q0.w};                                                     \
    a0 = FMA2(wa1, h, a0); a1 = FMA2(wb1, h, a1);                              \
    h = f32x2{r0.z, r0.w}; a1 = FMA2(wc1, h, a1);                              \
    h = f32x2{q1.x, q1.y};                                                     \
    a0 = FMA2(wa2, h, a0); a1 = FMA2(wb2, h, a1);                              \
    h = f32x2{r1.x, r1.y}; a1 = FMA2(wc2, h, a1);                              \
    h = f32x2{q1.z, q1.w};                                                     \
    a0 = FMA2(wa3, h, a0); a1 = FMA2(wb3, h, a1);                              \
    h = f32x2{r1.z, r1.w}; a1 = FMA2(wc3, h, a1);                              \
    h = f32x2{q2.x, q2.y};                                                     \
    a0 = FMA2(wa4, h, a0); a1 = FMA2(wb4, h, a1);                              \
    h = f32x2{r2.x, r2.y}; a1 = FMA2(wc4, h, a1);                              \
    h = f32x2{q2.z, q2.w};                                                     \
    a0 = FMA2(wa5, h, a0); a1 = FMA2(wb5, h, a1);                              \
    h = f32x2{r2.z, r2.w}; a1 = FMA2(wc5, h, a1);                              \
    h = f32x2{q3.x, q3.y};                                                     \
    a0 = FMA2(wa6, h, a0); a1 = FMA2(wb6, h, a1);                              \
    h = f32x2{r3.x, r3.y}; a1 = FMA2(wc6, h, a1);                              \
    h = f32x2{q3.z, q3.w};                                                     \
    a0 = FMA2(wa7, h, a0); a1 = FMA2(wb7, h, a1);                              \
    h = f32x2{r3.z, r3.w}; a1 = FMA2(wc7, h, a1);                              \
    const float acc0 = a0.x + a0.y;                                            \
    const float acc1 = a1.x + a1.y;                                            \
    const float act0 = fmaf(Aa, fast_rcp(1.0f + fast_exp2(acc0 * Ca)), Ba);    \
    const float act1 = fmaf(Aa, fast_rcp(1.0f + fast_exp2(acc1 * Ca)), Ba);    \
    const float sw0 = dppq<0x4E>(act0);        /* xor2: i<->g, f<->o */        \
    const float sw1 = dppq<0x4E>(act1);                                        \
    const float xp0 = dppq<0xB1>(act0 * sw0);  /* xor1: f-lane <- i*g */       \
    const float xp1 = dppq<0xB1>(act1 * sw1);                                  \
    const float c0n = fmaf(act0, cs0, xp0);    /* valid on f-lane (act0=f) */  \
    const float c1n = fmaf(sw1, cs1, xp1);     /* valid on o-lane (sw1=f1) */  \
    cs0 = c0n;                                                                 \
    if (DO_L1) cs1 = c1n;                                                      \
    const float tin = isF ? cs0 : cs1;                                         \
    const float e   = fast_exp2(fabsf(tin) * C2P);                             \
    float th = fmaf(-2.0f, fast_rcp(e + 1.0f), 1.0f);                          \
    th = copysignf(th, tin);                                                   \
    const float hv = (isF ? sw0 : act1) * th;  /* o0*tanh(c0) / o1*tanh(c1) */ \
    hs[wslot] = hv;                                                            \
  }

    for (int t0 = 0; t0 < TT; t0 += 4) {
        float4 xn = xq;
        if (t0 + 4 < TT) xn = *(const float4*)(xb + t0 + 4);
        LSTM_STEP(xq.x, (t0 != 0))
        LSTM_STEP(xq.y, true)
        LSTM_STEP(xq.z, true)
        LSTM_STEP(xq.w, true)
        xq = xn;
    }

    // ---- final L1 step: z^{511} from (z^{510}, h0^{511}) ----
    {
        const float4 q0 = *(const float4*)&hs[ 0];
        const float4 q1 = *(const float4*)&hs[ 4];
        const float4 q2 = *(const float4*)&hs[ 8];
        const float4 q3 = *(const float4*)&hs[12];
        const float4 r0 = *(const float4*)&hs[16];
        const float4 r1 = *(const float4*)&hs[20];
        const float4 r2 = *(const float4*)&hs[24];
        const float4 r3 = *(const float4*)&hs[28];
        f32x2 a1 = {bb1, 0.0f};
        f32x2 h;
        h = f32x2{q0.x, q0.y}; a1 = FMA2(wb0, h, a1);
        h = f32x2{r0.x, r0.y}; a1 = FMA2(wc0, h, a1);
        h = f32x2{q0.z, q0.w}; a1 = FMA2(wb1, h, a1);
        h = f32x2{r0.z, r0.w}; a1 = FMA2(wc1, h, a1);
        h = f32x2{q1.x, q1.y}; a1 = FMA2(wb2, h, a1);
        h = f32x2{r1.x, r1.y}; a1 = FMA2(wc2, h, a1);
        h = f32x2{q1.z, q1.w}; a1 = FMA2(wb3, h, a1);
        h = f32x2{r1.z, r1.w}; a1 = FMA2(wc3, h, a1);
        h = f32x2{q2.x, q2.y}; a1 = FMA2(wb4, h, a1);
        h = f32x2{r2.x, r2.y}; a1 = FMA2(wc4, h, a1);
        h = f32x2{q2.z, q2.w}; a1 = FMA2(wb5, h, a1);
        h = f32x2{r2.z, r2.w}; a1 = FMA2(wc5, h, a1);
        h = f32x2{q3.x, q3.y}; a1 = FMA2(wb6, h, a1);
        h = f32x2{r3.x, r3.y}; a1 = FMA2(wc6, h, a1);
        h = f32x2{q3.z, q3.w}; a1 = FMA2(wb7, h, a1);
        h = f32x2{r3.z, r3.w}; a1 = FMA2(wc7, h, a1);
        const float acc1 = a1.x + a1.y;
        const float act1 = fmaf(Aa, fast_rcp(1.0f + fast_exp2(acc1 * Ca)), Ba);
        const float sw1 = dppq<0x4E>(act1);
        const float xp1 = dppq<0xB1>(act1 * sw1);
        cs1 = fmaf(sw1, cs1, xp1);                 // valid on o-lane
        const float e = fast_exp2(fabsf(cs1) * C2P);
        float th = fmaf(-2.0f, fast_rcp(e + 1.0f), 1.0f);
        th = copysignf(th, cs1);
        const float h1fin = act1 * th;             // valid on o-lane

        // FC: out[b] = sum_j h1_j * W_fc[j] + b_fc
        const float wfc = W_fc[j];
        float p = (g == 3) ? h1fin * wfc : 0.0f;
        #pragma unroll
        for (int m = 1; m < 64; m <<= 1) p += __shfl_xor(p, m);
        if (l == 0) out[b] = p + b_fc[0];
    }
#undef LSTM_STEP
}

extern "C" void kernel_launch(void* const* d_in, const int* in_sizes, int n_in,
                              void* d_out, int out_size, void* d_ws, size_t ws_size,
                              hipStream_t stream) {
    const float* x     = (const float*)d_in[0];
    const float* W_ih0 = (const float*)d_in[1];
    const float* W_hh0 = (const float*)d_in[2];
    const float* b_ih0 = (const float*)d_in[3];
    const float* b_hh0 = (const float*)d_in[4];
    const float* W_ih1 = (const float*)d_in[5];
    const float* W_hh1 = (const float*)d_in[6];
    const float* b_ih1 = (const float*)d_in[7];
    const float* b_hh1 = (const float*)d_in[8];
    const float* W_fc  = (const float*)d_in[9];
    const float* b_fc  = (const float*)d_in[10];
    float* out = (float*)d_out;

    dim3 grid(4096), block(64);
    hipLaunchKernelGGL(lstm2_wave, grid, block, 0, stream,
                       x, W_ih0, W_hh0, b_ih0, b_hh0,
                       W_ih1, W_hh1, b_ih1, b_hh1, W_fc, b_fc, out);
}